// Round 1
// baseline (788.579 us; speedup 1.0000x reference)
//
#include <hip/hip_runtime.h>

// BasicRNN: h=[S|I|O] (256x4096); h' = relu(h @ W + g*[E,0,0]); out = h[:,3072:] @ out_w^T + out_b
// Strategy: bf16 MFMA (32x32x16), W pre-transposed to WT[n][k] so A and B fragments are
// single contiguous 16B global loads per lane (no LDS, no barriers). fp32 accumulate.

typedef __bf16 bf16x8 __attribute__((ext_vector_type(8)));
typedef float  f32x16 __attribute__((ext_vector_type(16)));

#define TOTAL   4096
#define BATCH   256
#define INDIM   2048
#define SDIM    1024
#define NCLS    1000

__device__ inline f32x16 zero16() {
    f32x16 v;
#pragma unroll
    for (int i = 0; i < 16; ++i) v[i] = 0.f;
    return v;
}

// ---- W (4096x4096 f32) -> WT (4096x4096 bf16), WT[n][k] = W[k][n] ----
__global__ __launch_bounds__(256) void k_transW(const float* __restrict__ W,
                                                __bf16* __restrict__ WT) {
    __shared__ float t[64][65];
    const int n0 = blockIdx.x * 64;
    const int k0 = blockIdx.y * 64;
    const int x = threadIdx.x;   // 0..63
    const int y = threadIdx.y;   // 0..3
#pragma unroll
    for (int r = y; r < 64; r += 4)
        t[r][x] = W[(size_t)(k0 + r) * TOTAL + (n0 + x)];
    __syncthreads();
#pragma unroll
    for (int r = y; r < 64; r += 4)
        WT[(size_t)(n0 + r) * TOTAL + (k0 + x)] = (__bf16)t[x][r];
}

// ---- f32 -> bf16 elementwise ----
__global__ __launch_bounds__(256) void k_cvt(const float* __restrict__ s,
                                             __bf16* __restrict__ d, int n) {
    int i = blockIdx.x * blockDim.x + threadIdx.x;
    if (i < n) d[i] = (__bf16)s[i];
}

// ---- E = x @ in_w^T + in_b ; h0[:, :1024] = relu(E) (bf16), E kept f32 ----
// grid 128 blocks x 128 thr; wave tile 32x32; K = 2048
__global__ __launch_bounds__(128) void k_gemm_E(const __bf16* __restrict__ xb,
                                                const __bf16* __restrict__ iwb,
                                                const float* __restrict__ in_b,
                                                float* __restrict__ E,
                                                __bf16* __restrict__ h0) {
    const int wave = threadIdx.x >> 6;
    const int lane = threadIdx.x & 63;
    const int nt  = blockIdx.x & 31;   // 32 n-tiles (s dim)
    const int mtp = blockIdx.x >> 5;   // 0..3
    const int m0 = (mtp * 2 + wave) * 32;
    const int n0 = nt * 32;
    const int l31 = lane & 31;
    const int kh  = (lane >> 5) * 8;
    const bf16x8* Ap = (const bf16x8*)(xb  + (size_t)(m0 + l31) * INDIM + kh);
    const bf16x8* Bp = (const bf16x8*)(iwb + (size_t)(n0 + l31) * INDIM + kh);
    f32x16 ac0 = zero16(), ac1 = zero16(), ac2 = zero16(), ac3 = zero16();
    for (int k = 0; k < INDIM; k += 64) {
        const int i = k >> 3;
        bf16x8 a0 = Ap[i + 0], b0 = Bp[i + 0];
        bf16x8 a1 = Ap[i + 2], b1 = Bp[i + 2];
        bf16x8 a2 = Ap[i + 4], b2 = Bp[i + 4];
        bf16x8 a3 = Ap[i + 6], b3 = Bp[i + 6];
        ac0 = __builtin_amdgcn_mfma_f32_32x32x16_bf16(a0, b0, ac0, 0, 0, 0);
        ac1 = __builtin_amdgcn_mfma_f32_32x32x16_bf16(a1, b1, ac1, 0, 0, 0);
        ac2 = __builtin_amdgcn_mfma_f32_32x32x16_bf16(a2, b2, ac2, 0, 0, 0);
        ac3 = __builtin_amdgcn_mfma_f32_32x32x16_bf16(a3, b3, ac3, 0, 0, 0);
    }
    f32x16 acc = (ac0 + ac1) + (ac2 + ac3);
    const int rbase = 4 * (lane >> 5);
    const int cn = n0 + l31;
    const float bias = in_b[cn];
#pragma unroll
    for (int r = 0; r < 16; ++r) {
        int cm = m0 + (r & 3) + 8 * (r >> 2) + rbase;
        float v = acc[r] + bias;
        E[cm * SDIM + cn] = v;
        h0[(size_t)cm * TOTAL + cn] = (__bf16)fmaxf(v, 0.f);
    }
}

// ---- one recurrence step: hn = relu(h @ W + gate*[E,0,0]) ----
// grid 512 blocks x 128 thr (2 waves); wave tile 32x32; K = 4096; 4 acc chains
__global__ __launch_bounds__(128) void k_step(const __bf16* __restrict__ h,
                                              const __bf16* __restrict__ WT,
                                              const float* __restrict__ E,
                                              const int gate,
                                              __bf16* __restrict__ hn) {
    const int wave = threadIdx.x >> 6;
    const int lane = threadIdx.x & 63;
    const int nt  = blockIdx.x & 127;  // 128 n-tiles of 32
    const int mtp = blockIdx.x >> 7;   // 0..3 (m-tile pairs)
    const int m0 = (mtp * 2 + wave) * 32;
    const int n0 = nt * 32;
    const int l31 = lane & 31;
    const int kh  = (lane >> 5) * 8;
    const bf16x8* Ap = (const bf16x8*)(h  + (size_t)(m0 + l31) * TOTAL + kh);
    const bf16x8* Bp = (const bf16x8*)(WT + (size_t)(n0 + l31) * TOTAL + kh);
    f32x16 ac0 = zero16(), ac1 = zero16(), ac2 = zero16(), ac3 = zero16();
    for (int k = 0; k < TOTAL; k += 64) {
        const int i = k >> 3;
        bf16x8 a0 = Ap[i + 0], b0 = Bp[i + 0];
        bf16x8 a1 = Ap[i + 2], b1 = Bp[i + 2];
        bf16x8 a2 = Ap[i + 4], b2 = Bp[i + 4];
        bf16x8 a3 = Ap[i + 6], b3 = Bp[i + 6];
        ac0 = __builtin_amdgcn_mfma_f32_32x32x16_bf16(a0, b0, ac0, 0, 0, 0);
        ac1 = __builtin_amdgcn_mfma_f32_32x32x16_bf16(a1, b1, ac1, 0, 0, 0);
        ac2 = __builtin_amdgcn_mfma_f32_32x32x16_bf16(a2, b2, ac2, 0, 0, 0);
        ac3 = __builtin_amdgcn_mfma_f32_32x32x16_bf16(a3, b3, ac3, 0, 0, 0);
    }
    f32x16 acc = (ac0 + ac1) + (ac2 + ac3);
    const int rbase = 4 * (lane >> 5);
    const int cn = n0 + l31;
    const bool addE = (gate != 0) && (cn < SDIM);
#pragma unroll
    for (int r = 0; r < 16; ++r) {
        int cm = m0 + (r & 3) + 8 * (r >> 2) + rbase;
        float v = acc[r];
        if (addE) v += E[cm * SDIM + cn];
        hn[(size_t)cm * TOTAL + cn] = (__bf16)fmaxf(v, 0.f);
    }
}

// ---- out = h[:, 3072:] @ out_w^T + out_b  (N=1000 padded to 1024) ----
__global__ __launch_bounds__(128) void k_out(const __bf16* __restrict__ hf,
                                             const __bf16* __restrict__ owb,
                                             const float* __restrict__ out_b,
                                             float* __restrict__ out) {
    const int wave = threadIdx.x >> 6;
    const int lane = threadIdx.x & 63;
    const int ct  = blockIdx.x & 31;   // 32 c-tiles
    const int mtp = blockIdx.x >> 5;   // 0..3
    const int m0 = (mtp * 2 + wave) * 32;
    const int c0 = ct * 32;
    const int l31 = lane & 31;
    const int kh  = (lane >> 5) * 8;
    const int cload = min(c0 + l31, NCLS - 1);
    const bf16x8* Ap = (const bf16x8*)(hf + (size_t)(m0 + l31) * TOTAL + 3072 + kh);
    const bf16x8* Bp = (const bf16x8*)(owb + (size_t)cload * 1024 + kh);
    f32x16 ac0 = zero16(), ac1 = zero16(), ac2 = zero16(), ac3 = zero16();
    for (int k = 0; k < 1024; k += 64) {
        const int i = k >> 3;
        bf16x8 a0 = Ap[i + 0], b0 = Bp[i + 0];
        bf16x8 a1 = Ap[i + 2], b1 = Bp[i + 2];
        bf16x8 a2 = Ap[i + 4], b2 = Bp[i + 4];
        bf16x8 a3 = Ap[i + 6], b3 = Bp[i + 6];
        ac0 = __builtin_amdgcn_mfma_f32_32x32x16_bf16(a0, b0, ac0, 0, 0, 0);
        ac1 = __builtin_amdgcn_mfma_f32_32x32x16_bf16(a1, b1, ac1, 0, 0, 0);
        ac2 = __builtin_amdgcn_mfma_f32_32x32x16_bf16(a2, b2, ac2, 0, 0, 0);
        ac3 = __builtin_amdgcn_mfma_f32_32x32x16_bf16(a3, b3, ac3, 0, 0, 0);
    }
    f32x16 acc = (ac0 + ac1) + (ac2 + ac3);
    const int rbase = 4 * (lane >> 5);
    const int cn = c0 + l31;
    if (cn < NCLS) {
        const float bias = out_b[cn];
#pragma unroll
        for (int r = 0; r < 16; ++r) {
            int cm = m0 + (r & 3) + 8 * (r >> 2) + rbase;
            out[cm * NCLS + cn] = acc[r] + bias;
        }
    }
}

extern "C" void kernel_launch(void* const* d_in, const int* in_sizes, int n_in,
                              void* d_out, int out_size, void* d_ws, size_t ws_size,
                              hipStream_t stream) {
    const float* x     = (const float*)d_in[0];   // 256 x 2048
    const float* W     = (const float*)d_in[1];   // 4096 x 4096
    const float* in_w  = (const float*)d_in[2];   // 1024 x 2048
    const float* in_b  = (const float*)d_in[3];   // 1024
    const float* out_w = (const float*)d_in[4];   // 1000 x 1024
    const float* out_b = (const float*)d_in[5];   // 1000
    float* out = (float*)d_out;                   // 256 x 1000

    char* ws = (char*)d_ws;
    // ws layout (bytes)
    __bf16* WT  = (__bf16*)(ws + 0);          // 32 MiB   4096x4096 bf16 (W^T)
    __bf16* XB  = (__bf16*)(ws + 33554432);   // 1 MiB    x bf16
    __bf16* IWB = (__bf16*)(ws + 34603008);   // 4 MiB    in_w bf16
    __bf16* OWB = (__bf16*)(ws + 38797312);   // ~2 MiB   out_w bf16
    float*  Ebuf= (float*)(ws + 40845312);    // 1 MiB    E f32
    __bf16* H0  = (__bf16*)(ws + 41893888);   // 2 MiB
    __bf16* H1  = (__bf16*)(ws + 43991040);   // 2 MiB

    k_transW<<<dim3(64, 64), dim3(64, 4), 0, stream>>>(W, WT);
    k_cvt<<<2048, 256, 0, stream>>>(x, XB, BATCH * INDIM);
    k_cvt<<<8192, 256, 0, stream>>>(in_w, IWB, SDIM * INDIM);
    k_cvt<<<4000, 256, 0, stream>>>(out_w, OWB, NCLS * 1024);
    hipMemsetAsync(H0, 0, (size_t)BATCH * TOTAL * sizeof(__bf16), stream);

    // t = 0: h = [relu(E), 0, 0] (gate=1, h was zero)
    k_gemm_E<<<128, 128, 0, stream>>>(XB, IWB, in_b, Ebuf, H0);

    // t = 1..9 (gate fires at t=5)
    const __bf16* hs = H0;
    __bf16* hd = H1;
    for (int t = 1; t < 10; ++t) {
        k_step<<<512, 128, 0, stream>>>(hs, WT, Ebuf, (t % 5 == 0) ? 1 : 0, hd);
        const __bf16* tmp = hs; hs = hd; hd = (__bf16*)tmp;
    }

    k_out<<<128, 128, 0, stream>>>(hs, OWB, out_b, out);
}

// Round 2
// 621.223 us; speedup vs baseline: 1.2694x; 1.2694x over previous
//
#include <hip/hip_runtime.h>

// BasicRNN: h=[S|I|O] (256x4096); h' = relu(h @ W + g*[E,0,0]); out = h[:,3072:] @ out_w^T + out_b
// R1: latency-bound fix. Each block = 8 waves splitting K in-register over one C-tile,
// LDS tree-less reduce, 16 waves/CU. bf16 MFMA 32x32x16, W pre-transposed (WT[n][k]) so
// A/B fragments are single contiguous 16B global loads (no LDS staging, no K-loop barriers).

typedef __bf16 bf16x8 __attribute__((ext_vector_type(8)));
typedef float  f32x16 __attribute__((ext_vector_type(16)));

#define TOTAL   4096
#define BATCH   256
#define INDIM   2048
#define SDIM    1024
#define NCLS    1000

__device__ inline f32x16 zero16() {
    f32x16 v;
#pragma unroll
    for (int i = 0; i < 16; ++i) v[i] = 0.f;
    return v;
}

// ---- W (4096x4096 f32) -> WT (4096x4096 bf16), WT[n][k] = W[k][n] ----
__global__ __launch_bounds__(256) void k_transW(const float* __restrict__ W,
                                                __bf16* __restrict__ WT) {
    __shared__ float t[64][65];
    const int n0 = blockIdx.x * 64;
    const int k0 = blockIdx.y * 64;
    const int x = threadIdx.x;   // 0..63
    const int y = threadIdx.y;   // 0..3
#pragma unroll
    for (int r = y; r < 64; r += 4)
        t[r][x] = W[(size_t)(k0 + r) * TOTAL + (n0 + x)];
    __syncthreads();
#pragma unroll
    for (int r = y; r < 64; r += 4)
        WT[(size_t)(n0 + r) * TOTAL + (k0 + x)] = (__bf16)t[x][r];
}

// ---- f32 -> bf16 elementwise ----
__global__ __launch_bounds__(256) void k_cvt(const float* __restrict__ s,
                                             __bf16* __restrict__ d, int n) {
    int i = blockIdx.x * blockDim.x + threadIdx.x;
    if (i < n) d[i] = (__bf16)s[i];
}

// ---- E = x @ in_w^T + in_b ; h0[:, :1024] = relu(E) ----
// 256 blocks x 512 thr; block tile 32x32; 8 waves K-split (K=256 each)
__global__ __launch_bounds__(512, 4) void k_gemm_E(const __bf16* __restrict__ xb,
                                                   const __bf16* __restrict__ iwb,
                                                   const float* __restrict__ in_b,
                                                   float* __restrict__ E,
                                                   __bf16* __restrict__ h0) {
    __shared__ float red[8][1024];
    const int wave = threadIdx.x >> 6;
    const int lane = threadIdx.x & 63;
    const int mt = blockIdx.x >> 5;    // 0..7
    const int nt = blockIdx.x & 31;    // 0..31
    const int m0 = mt * 32, n0 = nt * 32;
    const int l31 = lane & 31;
    const int kh  = (lane >> 5) * 8;
    const int kb  = wave * 256;
    const bf16x8* Ap = (const bf16x8*)xb  + (size_t)(m0 + l31) * (INDIM / 8) + ((kb + kh) >> 3);
    const bf16x8* Bp = (const bf16x8*)iwb + (size_t)(n0 + l31) * (INDIM / 8) + ((kb + kh) >> 3);
    f32x16 acc = zero16();
    for (int i = 0; i < 8; ++i) {
        const int off = i * 4;
        bf16x8 a0 = Ap[off], b0 = Bp[off];
        bf16x8 a1 = Ap[off + 2], b1 = Bp[off + 2];
        acc = __builtin_amdgcn_mfma_f32_32x32x16_bf16(a0, b0, acc, 0, 0, 0);
        acc = __builtin_amdgcn_mfma_f32_32x32x16_bf16(a1, b1, acc, 0, 0, 0);
    }
#pragma unroll
    for (int r = 0; r < 16; ++r) {
        int row = (r & 3) + 8 * (r >> 2) + 4 * (lane >> 5);
        red[wave][row * 32 + l31] = acc[r];
    }
    __syncthreads();
    const int e0 = threadIdx.x * 2;
    float sx = 0.f, sy = 0.f;
#pragma unroll
    for (int w = 0; w < 8; ++w) {
        float2 v = *(const float2*)&red[w][e0];
        sx += v.x; sy += v.y;
    }
    const int row = e0 >> 5, col = e0 & 31;
    const int m = m0 + row, n = n0 + col;
    float v0 = sx + in_b[n], v1 = sy + in_b[n + 1];
    E[m * SDIM + n]     = v0;
    E[m * SDIM + n + 1] = v1;
    h0[(size_t)m * TOTAL + n]     = (__bf16)fmaxf(v0, 0.f);
    h0[(size_t)m * TOTAL + n + 1] = (__bf16)fmaxf(v1, 0.f);
}

// ---- one recurrence step: hn = relu(h @ W + gate*[E,0,0]) ----
// 512 blocks x 512 thr; block tile 64(m)x32(n); 8 waves K-split (K=512 each)
__global__ __launch_bounds__(512, 4) void k_step(const __bf16* __restrict__ h,
                                                 const __bf16* __restrict__ WT,
                                                 const float* __restrict__ E,
                                                 const int gate,
                                                 __bf16* __restrict__ hn) {
    __shared__ float red[8][2048];   // 64 KiB
    const int wave = threadIdx.x >> 6;
    const int lane = threadIdx.x & 63;
    const int mt = blockIdx.x >> 7;    // 0..3  -> m0 = mt*64
    const int nt = blockIdx.x & 127;   // 0..127 -> n0 = nt*32
    const int m0 = mt * 64, n0 = nt * 32;
    const int l31 = lane & 31;
    const int kh  = (lane >> 5) * 8;
    const int kb  = wave * 512;
    const bf16x8* A0 = (const bf16x8*)h  + (size_t)(m0 + l31) * (TOTAL / 8) + ((kb + kh) >> 3);
    const bf16x8* A1 = A0 + 32 * (TOTAL / 8);
    const bf16x8* Bp = (const bf16x8*)WT + (size_t)(n0 + l31) * (TOTAL / 8) + ((kb + kh) >> 3);
    f32x16 ac0 = zero16(), ac1 = zero16();
    for (int i = 0; i < 16; ++i) {
        const int off = i * 4;
        bf16x8 a00 = A0[off],     a10 = A1[off],     b0 = Bp[off];
        bf16x8 a01 = A0[off + 2], a11 = A1[off + 2], b1 = Bp[off + 2];
        ac0 = __builtin_amdgcn_mfma_f32_32x32x16_bf16(a00, b0, ac0, 0, 0, 0);
        ac1 = __builtin_amdgcn_mfma_f32_32x32x16_bf16(a10, b0, ac1, 0, 0, 0);
        ac0 = __builtin_amdgcn_mfma_f32_32x32x16_bf16(a01, b1, ac0, 0, 0, 0);
        ac1 = __builtin_amdgcn_mfma_f32_32x32x16_bf16(a11, b1, ac1, 0, 0, 0);
    }
#pragma unroll
    for (int r = 0; r < 16; ++r) {
        int row = (r & 3) + 8 * (r >> 2) + 4 * (lane >> 5);
        red[wave][row * 32 + l31]        = ac0[r];
        red[wave][(row + 32) * 32 + l31] = ac1[r];
    }
    __syncthreads();
    // 2048 elements, 512 threads x 4 (float4)
    const int e0 = threadIdx.x * 4;
    float4 s = {0.f, 0.f, 0.f, 0.f};
#pragma unroll
    for (int w = 0; w < 8; ++w) {
        float4 v = *(const float4*)&red[w][e0];
        s.x += v.x; s.y += v.y; s.z += v.z; s.w += v.w;
    }
    const int row = e0 >> 5, col = e0 & 31;
    const int m = m0 + row;
    const int n = n0 + col;
    if (gate && n0 < SDIM) {
        const float* Ep = E + m * SDIM + n;
        s.x += Ep[0]; s.y += Ep[1]; s.z += Ep[2]; s.w += Ep[3];
    }
    __bf16 o[4];
    o[0] = (__bf16)fmaxf(s.x, 0.f);
    o[1] = (__bf16)fmaxf(s.y, 0.f);
    o[2] = (__bf16)fmaxf(s.z, 0.f);
    o[3] = (__bf16)fmaxf(s.w, 0.f);
    *(ushort4*)(hn + (size_t)m * TOTAL + n) = *(const ushort4*)o;
}

// ---- out = h[:, 3072:] @ out_w^T + out_b  (N=1000 padded to 1024) ----
// 256 blocks x 512 thr; block tile 32x32; 8 waves K-split (K=128 each)
__global__ __launch_bounds__(512, 4) void k_out(const __bf16* __restrict__ hf,
                                                const __bf16* __restrict__ owb,
                                                const float* __restrict__ out_b,
                                                float* __restrict__ out) {
    __shared__ float red[8][1024];
    const int wave = threadIdx.x >> 6;
    const int lane = threadIdx.x & 63;
    const int mt = blockIdx.x >> 5;    // 0..7
    const int ct = blockIdx.x & 31;    // 0..31
    const int m0 = mt * 32, c0 = ct * 32;
    const int l31 = lane & 31;
    const int kh  = (lane >> 5) * 8;
    const int kb  = wave * 128;
    const int cload = min(c0 + l31, NCLS - 1);
    const bf16x8* Ap = (const bf16x8*)(hf + 3072) + (size_t)(m0 + l31) * (TOTAL / 8) + ((kb + kh) >> 3);
    const bf16x8* Bp = (const bf16x8*)owb + (size_t)cload * (1024 / 8) + ((kb + kh) >> 3);
    f32x16 acc = zero16();
    for (int i = 0; i < 4; ++i) {
        const int off = i * 4;
        bf16x8 a0 = Ap[off], b0 = Bp[off];
        bf16x8 a1 = Ap[off + 2], b1 = Bp[off + 2];
        acc = __builtin_amdgcn_mfma_f32_32x32x16_bf16(a0, b0, acc, 0, 0, 0);
        acc = __builtin_amdgcn_mfma_f32_32x32x16_bf16(a1, b1, acc, 0, 0, 0);
    }
#pragma unroll
    for (int r = 0; r < 16; ++r) {
        int row = (r & 3) + 8 * (r >> 2) + 4 * (lane >> 5);
        red[wave][row * 32 + l31] = acc[r];
    }
    __syncthreads();
    const int e0 = threadIdx.x * 2;
    float sx = 0.f, sy = 0.f;
#pragma unroll
    for (int w = 0; w < 8; ++w) {
        float2 v = *(const float2*)&red[w][e0];
        sx += v.x; sy += v.y;
    }
    const int row = e0 >> 5, col = e0 & 31;
    const int m = m0 + row;
    const int n = c0 + col;
    if (n < NCLS)     out[m * NCLS + n]     = sx + out_b[n];
    if (n + 1 < NCLS) out[m * NCLS + n + 1] = sy + out_b[n + 1];
}

extern "C" void kernel_launch(void* const* d_in, const int* in_sizes, int n_in,
                              void* d_out, int out_size, void* d_ws, size_t ws_size,
                              hipStream_t stream) {
    const float* x     = (const float*)d_in[0];   // 256 x 2048
    const float* W     = (const float*)d_in[1];   // 4096 x 4096
    const float* in_w  = (const float*)d_in[2];   // 1024 x 2048
    const float* in_b  = (const float*)d_in[3];   // 1024
    const float* out_w = (const float*)d_in[4];   // 1000 x 1024
    const float* out_b = (const float*)d_in[5];   // 1000
    float* out = (float*)d_out;                   // 256 x 1000

    char* ws = (char*)d_ws;
    __bf16* WT  = (__bf16*)(ws + 0);          // 32 MiB   4096x4096 bf16 (W^T)
    __bf16* XB  = (__bf16*)(ws + 33554432);   // 1 MiB    x bf16
    __bf16* IWB = (__bf16*)(ws + 34603008);   // 4 MiB    in_w bf16
    __bf16* OWB = (__bf16*)(ws + 38797312);   // ~2 MiB   out_w bf16
    float*  Ebuf= (float*)(ws + 40845312);    // 1 MiB    E f32
    __bf16* H0  = (__bf16*)(ws + 41893888);   // 2 MiB
    __bf16* H1  = (__bf16*)(ws + 43991040);   // 2 MiB

    k_transW<<<dim3(64, 64), dim3(64, 4), 0, stream>>>(W, WT);
    k_cvt<<<2048, 256, 0, stream>>>(x, XB, BATCH * INDIM);
    k_cvt<<<8192, 256, 0, stream>>>(in_w, IWB, SDIM * INDIM);
    k_cvt<<<4000, 256, 0, stream>>>(out_w, OWB, NCLS * 1024);
    hipMemsetAsync(H0, 0, (size_t)BATCH * TOTAL * sizeof(__bf16), stream);

    // t = 0: h = [relu(E), 0, 0] (gate=1, h was zero)
    k_gemm_E<<<256, 512, 0, stream>>>(XB, IWB, in_b, Ebuf, H0);

    // t = 1..9 (gate fires at t=5)
    const __bf16* hs = H0;
    __bf16* hd = H1;
    for (int t = 1; t < 10; ++t) {
        k_step<<<512, 512, 0, stream>>>(hs, WT, Ebuf, (t % 5 == 0) ? 1 : 0, hd);
        const __bf16* tmp = hs; hs = hd; hd = (__bf16*)tmp;
    }

    k_out<<<256, 512, 0, stream>>>(hs, OWB, out_b, out);
}

// Round 3
// 322.128 us; speedup vs baseline: 2.4480x; 1.9285x over previous
//
#include <hip/hip_runtime.h>

// BasicRNN R2: fragment-major tiled operand layout so every MFMA fragment load is one
// contiguous 1KB coalesced global_load_dwordx4 (R1 was TA-transaction-bound: strided
// 16B/lane loads = 32 transactions/instr). Fragment unit = 32 rows x 16 K = 512 bf16:
//   addr(r,c) elems = frag*512 + lane*8 + (c&7),  frag = (r>>5)*(C/16) + (c>>4),
//   lane = (r&31) + 32*((c>>3)&1)    -- exactly the 32x32x16 bf16 A/B fragment map.

typedef __bf16 bf16x8 __attribute__((ext_vector_type(8)));
typedef float  f32x16 __attribute__((ext_vector_type(16)));

#define TOTAL   4096
#define BATCH   256
#define INDIM   2048
#define SDIM    1024
#define NCLS    1000

__device__ inline f32x16 zero16() {
    f32x16 v;
#pragma unroll
    for (int i = 0; i < 16; ++i) v[i] = 0.f;
    return v;
}

// ---- W (4096x4096 f32, W[k][n]) -> WT tiled bf16 with r=n, c=k ----
__global__ __launch_bounds__(256) void k_transW_swz(const float* __restrict__ W,
                                                    __bf16* __restrict__ WT) {
    __shared__ float t[64][65];
    const int n0 = blockIdx.x * 64;   // output r (n) base
    const int k0 = blockIdx.y * 64;   // output c (k) base
    const int x = threadIdx.x & 63;
    const int y = threadIdx.x >> 6;   // 0..3
#pragma unroll
    for (int r = y; r < 64; r += 4)
        t[r][x] = W[(size_t)(k0 + r) * TOTAL + (n0 + x)];
    __syncthreads();
#pragma unroll
    for (int s = threadIdx.x; s < 512; s += 256) {
        const int frag = s >> 6;        // 0..7 (2 rt x 4 kc)
        const int lane = s & 63;
        const int lrt = frag >> 2;
        const int lkc = frag & 3;
        const int r_local = lrt * 32 + (lane & 31);
        const int c_local = lkc * 16 + (lane >> 5) * 8;
        alignas(16) __bf16 v[8];
#pragma unroll
        for (int j = 0; j < 8; ++j) v[j] = (__bf16)t[c_local + j][r_local];
        const size_t fragG = (size_t)((n0 >> 5) + lrt) * (TOTAL / 16) + ((k0 >> 4) + lkc);
        *(ulonglong2*)(WT + fragG * 512 + lane * 8) = *(const ulonglong2*)v;
    }
}

// ---- row-major f32 [R x C] -> fragment-tiled bf16 (rows >= Rvalid zeroed) ----
__global__ __launch_bounds__(256) void k_swz(const float* __restrict__ in,
                                             __bf16* __restrict__ out,
                                             int C, int Rvalid) {
    const int t = blockIdx.x * blockDim.x + threadIdx.x;  // slot id
    const int lane = t & 63;
    const int frag = t >> 6;
    const int kcN = C >> 4;
    const int rt = frag / kcN;
    const int kc = frag - rt * kcN;
    const int r = rt * 32 + (lane & 31);
    const int c = kc * 16 + (lane >> 5) * 8;
    alignas(16) __bf16 v[8];
    if (r < Rvalid) {
        const float* p = in + (size_t)r * C + c;
#pragma unroll
        for (int j = 0; j < 8; ++j) v[j] = (__bf16)p[j];
    } else {
#pragma unroll
        for (int j = 0; j < 8; ++j) v[j] = (__bf16)0.f;
    }
    *(ulonglong2*)(out + (size_t)t * 8) = *(const ulonglong2*)v;
}

// ---- E = x @ in_w^T + in_b ; h0[:, :1024] = relu(E) (tiled) ----
// 256 blocks x 512 thr; tile 32x32; 8 waves K-split (256 each = 16 chunks)
__global__ __launch_bounds__(512, 4) void k_gemm_E(const __bf16* __restrict__ xt,
                                                   const __bf16* __restrict__ iwt,
                                                   const float* __restrict__ in_b,
                                                   float* __restrict__ E,
                                                   __bf16* __restrict__ h0) {
    __shared__ float red[8][1024];
    const int wave = threadIdx.x >> 6;
    const int lane = threadIdx.x & 63;
    const int mt = blockIdx.x >> 5;    // 0..7
    const int nt = blockIdx.x & 31;    // 0..31
    const int m0 = mt * 32, n0 = nt * 32;
    const int kc0 = wave * 16;
    const bf16x8* Ap = (const bf16x8*)xt  + ((size_t)mt * (INDIM / 16) + kc0) * 64 + lane;
    const bf16x8* Bp = (const bf16x8*)iwt + ((size_t)nt * (INDIM / 16) + kc0) * 64 + lane;
    f32x16 acc = zero16();
#pragma unroll 4
    for (int i = 0; i < 16; ++i) {
        bf16x8 a = Ap[i * 64];
        bf16x8 b = Bp[i * 64];
        acc = __builtin_amdgcn_mfma_f32_32x32x16_bf16(a, b, acc, 0, 0, 0);
    }
#pragma unroll
    for (int r = 0; r < 16; ++r) {
        int row = (r & 3) + 8 * (r >> 2) + 4 * (lane >> 5);
        red[wave][row * 32 + (lane & 31)] = acc[r];
    }
    __syncthreads();
    const int e0 = threadIdx.x * 2;
    float sx = 0.f, sy = 0.f;
#pragma unroll
    for (int w = 0; w < 8; ++w) {
        float2 v = *(const float2*)&red[w][e0];
        sx += v.x; sy += v.y;
    }
    const int row = e0 >> 5, col = e0 & 31;
    const int m = m0 + row, n = n0 + col;
    float v0 = sx + in_b[n], v1 = sy + in_b[n + 1];
    E[m * SDIM + n]     = v0;
    E[m * SDIM + n + 1] = v1;
    // tiled h0 write (2 consecutive n, n even)
    __bf16 o[2];
    o[0] = (__bf16)fmaxf(v0, 0.f);
    o[1] = (__bf16)fmaxf(v1, 0.f);
    const size_t frag = (size_t)(m >> 5) * (TOTAL / 16) + (n >> 4);
    const int lh = (m & 31) + 32 * ((n >> 3) & 1);
    *(uint*)(h0 + frag * 512 + lh * 8 + (n & 7)) = *(const uint*)o;
}

// ---- one recurrence step: hn = relu(h @ W + gate*[E,0,0]) (h, hn, WT all tiled) ----
// 512 blocks x 512 thr; tile 64m x 32n; 8 waves K-split (512 each = 32 chunks)
__global__ __launch_bounds__(512, 4) void k_step(const __bf16* __restrict__ h,
                                                 const __bf16* __restrict__ WT,
                                                 const float* __restrict__ E,
                                                 const int gate,
                                                 __bf16* __restrict__ hn) {
    __shared__ float red[8][2048];   // 64 KiB
    const int wave = threadIdx.x >> 6;
    const int lane = threadIdx.x & 63;
    const int mt = blockIdx.x >> 7;    // 0..3  -> m0 = mt*64
    const int nt = blockIdx.x & 127;   // 0..127 -> n0 = nt*32
    const int m0 = mt * 64, n0 = nt * 32;
    const int kc0 = wave * 32;
    const bf16x8* A0 = (const bf16x8*)h  + ((size_t)(mt * 2) * (TOTAL / 16) + kc0) * 64 + lane;
    const bf16x8* A1 = A0 + (size_t)(TOTAL / 16) * 64;
    const bf16x8* Bp = (const bf16x8*)WT + ((size_t)nt * (TOTAL / 16) + kc0) * 64 + lane;
    f32x16 ac0 = zero16(), ac1 = zero16();
#pragma unroll 4
    for (int i = 0; i < 32; ++i) {
        bf16x8 a0 = A0[i * 64];
        bf16x8 a1 = A1[i * 64];
        bf16x8 b  = Bp[i * 64];
        ac0 = __builtin_amdgcn_mfma_f32_32x32x16_bf16(a0, b, ac0, 0, 0, 0);
        ac1 = __builtin_amdgcn_mfma_f32_32x32x16_bf16(a1, b, ac1, 0, 0, 0);
    }
#pragma unroll
    for (int r = 0; r < 16; ++r) {
        int row = (r & 3) + 8 * (r >> 2) + 4 * (lane >> 5);
        red[wave][row * 32 + (lane & 31)]        = ac0[r];
        red[wave][(row + 32) * 32 + (lane & 31)] = ac1[r];
    }
    __syncthreads();
    const int e0 = threadIdx.x * 4;
    float4 s = {0.f, 0.f, 0.f, 0.f};
#pragma unroll
    for (int w = 0; w < 8; ++w) {
        float4 v = *(const float4*)&red[w][e0];
        s.x += v.x; s.y += v.y; s.z += v.z; s.w += v.w;
    }
    const int row = e0 >> 5, col = e0 & 31;
    const int m = m0 + row;
    const int n = n0 + col;
    if (gate && n0 < SDIM) {
        const float* Ep = E + m * SDIM + n;
        s.x += Ep[0]; s.y += Ep[1]; s.z += Ep[2]; s.w += Ep[3];
    }
    __bf16 o[4];
    o[0] = (__bf16)fmaxf(s.x, 0.f);
    o[1] = (__bf16)fmaxf(s.y, 0.f);
    o[2] = (__bf16)fmaxf(s.z, 0.f);
    o[3] = (__bf16)fmaxf(s.w, 0.f);
    // tiled hn write (4 consecutive n, n % 4 == 0 -> 8B aligned)
    const size_t frag = (size_t)(m >> 5) * (TOTAL / 16) + (n >> 4);
    const int lh = (m & 31) + 32 * ((n >> 3) & 1);
    *(ushort4*)(hn + frag * 512 + lh * 8 + (n & 7)) = *(const ushort4*)o;
}

// ---- out = h[:, 3072:] @ out_w^T + out_b (h tiled, out_w tiled padded to 1024 rows) ----
// 256 blocks x 512 thr; tile 32x32; 8 waves K-split (128 each = 8 chunks)
__global__ __launch_bounds__(512, 4) void k_out(const __bf16* __restrict__ h,
                                                const __bf16* __restrict__ owt,
                                                const float* __restrict__ out_b,
                                                float* __restrict__ out) {
    __shared__ float red[8][1024];
    const int wave = threadIdx.x >> 6;
    const int lane = threadIdx.x & 63;
    const int mt = blockIdx.x >> 5;    // 0..7
    const int ct = blockIdx.x & 31;    // 0..31
    const int m0 = mt * 32, c0 = ct * 32;
    const int kcA0 = (3072 / 16) + wave * 8;   // h columns 3072..4095
    const int kcB0 = wave * 8;
    const bf16x8* Ap = (const bf16x8*)h   + ((size_t)mt * (TOTAL / 16) + kcA0) * 64 + lane;
    const bf16x8* Bp = (const bf16x8*)owt + ((size_t)ct * (1024 / 16) + kcB0) * 64 + lane;
    f32x16 acc = zero16();
#pragma unroll
    for (int i = 0; i < 8; ++i) {
        bf16x8 a = Ap[i * 64];
        bf16x8 b = Bp[i * 64];
        acc = __builtin_amdgcn_mfma_f32_32x32x16_bf16(a, b, acc, 0, 0, 0);
    }
#pragma unroll
    for (int r = 0; r < 16; ++r) {
        int row = (r & 3) + 8 * (r >> 2) + 4 * (lane >> 5);
        red[wave][row * 32 + (lane & 31)] = acc[r];
    }
    __syncthreads();
    const int e0 = threadIdx.x * 2;
    float sx = 0.f, sy = 0.f;
#pragma unroll
    for (int w = 0; w < 8; ++w) {
        float2 v = *(const float2*)&red[w][e0];
        sx += v.x; sy += v.y;
    }
    const int row = e0 >> 5, col = e0 & 31;
    const int m = m0 + row;
    const int n = c0 + col;
    if (n < NCLS)     out[m * NCLS + n]     = sx + out_b[n];
    if (n + 1 < NCLS) out[m * NCLS + n + 1] = sy + out_b[n + 1];
}

extern "C" void kernel_launch(void* const* d_in, const int* in_sizes, int n_in,
                              void* d_out, int out_size, void* d_ws, size_t ws_size,
                              hipStream_t stream) {
    const float* x     = (const float*)d_in[0];   // 256 x 2048
    const float* W     = (const float*)d_in[1];   // 4096 x 4096
    const float* in_w  = (const float*)d_in[2];   // 1024 x 2048
    const float* in_b  = (const float*)d_in[3];   // 1024
    const float* out_w = (const float*)d_in[4];   // 1000 x 1024
    const float* out_b = (const float*)d_in[5];   // 1000
    float* out = (float*)d_out;                   // 256 x 1000

    char* ws = (char*)d_ws;
    __bf16* WT  = (__bf16*)(ws + 0);          // 32 MiB  W^T tiled (r=n, c=k)
    __bf16* XT  = (__bf16*)(ws + 33554432);   // 1 MiB   x tiled
    __bf16* IWT = (__bf16*)(ws + 34603008);   // 4 MiB   in_w tiled
    __bf16* OWT = (__bf16*)(ws + 38797312);   // 2 MiB   out_w tiled (padded 1024 rows)
    float*  Ebuf= (float*)(ws + 40894464);    // 1 MiB   E f32 row-major
    __bf16* H0  = (__bf16*)(ws + 41943040);   // 2 MiB   h tiled
    __bf16* H1  = (__bf16*)(ws + 44040192);   // 2 MiB   h tiled

    k_transW_swz<<<dim3(64, 64), 256, 0, stream>>>(W, WT);
    k_swz<<<256,  256, 0, stream>>>(x,     XT,  INDIM, BATCH);
    k_swz<<<1024, 256, 0, stream>>>(in_w,  IWT, INDIM, SDIM);
    k_swz<<<512,  256, 0, stream>>>(out_w, OWT, 1024,  NCLS);
    hipMemsetAsync(H0, 0, (size_t)BATCH * TOTAL * sizeof(__bf16), stream);

    // t = 0: h = [relu(E), 0, 0] (gate=1, h was zero)
    k_gemm_E<<<256, 512, 0, stream>>>(XT, IWT, in_b, Ebuf, H0);

    // t = 1..9 (gate fires at t=5)
    const __bf16* hs = H0;
    __bf16* hd = H1;
    for (int t = 1; t < 10; ++t) {
        k_step<<<512, 512, 0, stream>>>(hs, WT, Ebuf, (t % 5 == 0) ? 1 : 0, hd);
        const __bf16* tmp = hs; hs = hd; hd = (__bf16*)tmp;
    }

    k_out<<<256, 512, 0, stream>>>(hs, OWT, out_b, out);
}

// Round 4
// 278.078 us; speedup vs baseline: 2.8358x; 1.1584x over previous
//
#include <hip/hip_runtime.h>

// BasicRNN R3: k_step retiled to 64x64 wave-tile (4 acc chains), Tn=64 -> total logical
// traffic 384MB->256MB/step, 1KB/MFMA. 256 blocks x 8 waves, K-split 8, two-phase LDS
// reduce. Step t=1 uses K=1024 only (h1 = [relu(E),0,0]). Fragment-tiled operands as R2:
//   elem(r,c) = frag*512 + lane*8 + (c&7), frag = (r>>5)*(C/16)+(c>>4), lane=(r&31)+32*((c>>3)&1)

typedef __bf16 bf16x8 __attribute__((ext_vector_type(8)));
typedef float  f32x16 __attribute__((ext_vector_type(16)));

#define TOTAL   4096
#define BATCH   256
#define INDIM   2048
#define SDIM    1024
#define NCLS    1000

__device__ inline f32x16 zero16() {
    f32x16 v;
#pragma unroll
    for (int i = 0; i < 16; ++i) v[i] = 0.f;
    return v;
}

// ---- W (4096x4096 f32, W[k][n]) -> WT tiled bf16 with r=n, c=k ----
__global__ __launch_bounds__(256) void k_transW_swz(const float* __restrict__ W,
                                                    __bf16* __restrict__ WT) {
    __shared__ float t[64][65];
    const int n0 = blockIdx.x * 64;
    const int k0 = blockIdx.y * 64;
    const int x = threadIdx.x & 63;
    const int y = threadIdx.x >> 6;
#pragma unroll
    for (int r = y; r < 64; r += 4)
        t[r][x] = W[(size_t)(k0 + r) * TOTAL + (n0 + x)];
    __syncthreads();
#pragma unroll
    for (int s = threadIdx.x; s < 512; s += 256) {
        const int frag = s >> 6;
        const int lane = s & 63;
        const int lrt = frag >> 2;
        const int lkc = frag & 3;
        const int r_local = lrt * 32 + (lane & 31);
        const int c_local = lkc * 16 + (lane >> 5) * 8;
        alignas(16) __bf16 v[8];
#pragma unroll
        for (int j = 0; j < 8; ++j) v[j] = (__bf16)t[c_local + j][r_local];
        const size_t fragG = (size_t)((n0 >> 5) + lrt) * (TOTAL / 16) + ((k0 >> 4) + lkc);
        *(ulonglong2*)(WT + fragG * 512 + lane * 8) = *(const ulonglong2*)v;
    }
}

// ---- row-major f32 [R x C] -> fragment-tiled bf16 (rows >= Rvalid zeroed) ----
__global__ __launch_bounds__(256) void k_swz(const float* __restrict__ in,
                                             __bf16* __restrict__ out,
                                             int C, int Rvalid) {
    const int t = blockIdx.x * blockDim.x + threadIdx.x;
    const int lane = t & 63;
    const int frag = t >> 6;
    const int kcN = C >> 4;
    const int rt = frag / kcN;
    const int kc = frag - rt * kcN;
    const int r = rt * 32 + (lane & 31);
    const int c = kc * 16 + (lane >> 5) * 8;
    alignas(16) __bf16 v[8];
    if (r < Rvalid) {
        const float* p = in + (size_t)r * C + c;
#pragma unroll
        for (int j = 0; j < 8; ++j) v[j] = (__bf16)p[j];
    } else {
#pragma unroll
        for (int j = 0; j < 8; ++j) v[j] = (__bf16)0.f;
    }
    *(ulonglong2*)(out + (size_t)t * 8) = *(const ulonglong2*)v;
}

// ---- E = x @ in_w^T + in_b ; h0[:, :1024] = relu(E) (tiled) ----
__global__ __launch_bounds__(512, 4) void k_gemm_E(const __bf16* __restrict__ xt,
                                                   const __bf16* __restrict__ iwt,
                                                   const float* __restrict__ in_b,
                                                   float* __restrict__ E,
                                                   __bf16* __restrict__ h0) {
    __shared__ float red[8][1024];
    const int wave = threadIdx.x >> 6;
    const int lane = threadIdx.x & 63;
    const int mt = blockIdx.x >> 5;
    const int nt = blockIdx.x & 31;
    const int m0 = mt * 32, n0 = nt * 32;
    const int kc0 = wave * 16;
    const bf16x8* Ap = (const bf16x8*)xt  + ((size_t)mt * (INDIM / 16) + kc0) * 64 + lane;
    const bf16x8* Bp = (const bf16x8*)iwt + ((size_t)nt * (INDIM / 16) + kc0) * 64 + lane;
    f32x16 acc = zero16();
#pragma unroll 4
    for (int i = 0; i < 16; ++i) {
        bf16x8 a = Ap[i * 64];
        bf16x8 b = Bp[i * 64];
        acc = __builtin_amdgcn_mfma_f32_32x32x16_bf16(a, b, acc, 0, 0, 0);
    }
#pragma unroll
    for (int r = 0; r < 16; ++r) {
        int row = (r & 3) + 8 * (r >> 2) + 4 * (lane >> 5);
        red[wave][row * 32 + (lane & 31)] = acc[r];
    }
    __syncthreads();
    const int e0 = threadIdx.x * 2;
    float sx = 0.f, sy = 0.f;
#pragma unroll
    for (int w = 0; w < 8; ++w) {
        float2 v = *(const float2*)&red[w][e0];
        sx += v.x; sy += v.y;
    }
    const int row = e0 >> 5, col = e0 & 31;
    const int m = m0 + row, n = n0 + col;
    float v0 = sx + in_b[n], v1 = sy + in_b[n + 1];
    E[m * SDIM + n]     = v0;
    E[m * SDIM + n + 1] = v1;
    __bf16 o[2];
    o[0] = (__bf16)fmaxf(v0, 0.f);
    o[1] = (__bf16)fmaxf(v1, 0.f);
    const size_t frag = (size_t)(m >> 5) * (TOTAL / 16) + (n >> 4);
    const int lh = (m & 31) + 32 * ((n >> 3) & 1);
    *(uint*)(h0 + frag * 512 + lh * 8 + (n & 7)) = *(const uint*)o;
}

// ---- one recurrence step: hn = relu(h @ W + gate*[E,0,0]) (h, hn, WT tiled) ----
// 256 blocks x 512 thr; block/wave tile 64m x 64n; 8 waves K-split; chunks = K/16
__global__ __launch_bounds__(512, 2) void k_step(const __bf16* __restrict__ h,
                                                 const __bf16* __restrict__ WT,
                                                 const float* __restrict__ E,
                                                 const int gate,
                                                 __bf16* __restrict__ hn,
                                                 const int chunks) {
    __shared__ float buf[4][4096];   // 64 KiB
    const int wave = threadIdx.x >> 6;
    const int lane = threadIdx.x & 63;
    const int mt = blockIdx.x >> 6;    // 0..3  -> m0 = mt*64
    const int nt = blockIdx.x & 63;    // 0..63 -> n0 = nt*64
    const int per = chunks >> 3;
    const int kc0 = wave * per;

    const bf16x8* A0 = (const bf16x8*)h  + ((size_t)(mt * 2) * (TOTAL / 16) + kc0) * 64 + lane;
    const bf16x8* A1 = A0 + (size_t)(TOTAL / 16) * 64;
    const bf16x8* B0 = (const bf16x8*)WT + ((size_t)(nt * 2) * (TOTAL / 16) + kc0) * 64 + lane;
    const bf16x8* B1 = B0 + (size_t)(TOTAL / 16) * 64;

    f32x16 ac0 = zero16(), ac1 = zero16(), ac2 = zero16(), ac3 = zero16();
#pragma unroll 4
    for (int i = 0; i < per; ++i) {
        const int off = i * 64;
        bf16x8 a0 = A0[off];
        bf16x8 a1 = A1[off];
        bf16x8 b0 = B0[off];
        bf16x8 b1 = B1[off];
        ac0 = __builtin_amdgcn_mfma_f32_32x32x16_bf16(a0, b0, ac0, 0, 0, 0);
        ac1 = __builtin_amdgcn_mfma_f32_32x32x16_bf16(a0, b1, ac1, 0, 0, 0);
        ac2 = __builtin_amdgcn_mfma_f32_32x32x16_bf16(a1, b0, ac2, 0, 0, 0);
        ac3 = __builtin_amdgcn_mfma_f32_32x32x16_bf16(a1, b1, ac3, 0, 0, 0);
    }

    // two-phase reduce: layout idx(c,r,l) = (c*16+r)*64 + l  (2-way bank alias: free)
    float* accp[4];
    f32x16 accs[4] = {ac0, ac1, ac2, ac3};
    if (wave >= 4) {
        float* b = buf[wave - 4];
#pragma unroll
        for (int c = 0; c < 4; ++c)
#pragma unroll
            for (int r = 0; r < 16; ++r)
                b[(c * 16 + r) * 64 + lane] = accs[c][r];
    }
    __syncthreads();
    if (wave < 4) {
        float* b = buf[wave];
#pragma unroll
        for (int c = 0; c < 4; ++c)
#pragma unroll
            for (int r = 0; r < 16; ++r) {
                const int idx = (c * 16 + r) * 64 + lane;
                b[idx] += accs[c][r];
            }
    }
    __syncthreads();

    // final 4-way sum + epilogue; thread t -> (c, r, 8 lanes starting at l0)
    const int t = threadIdx.x;
    const int c = t >> 7;            // 0..3
    const int r = (t >> 3) & 15;     // 0..15
    const int l0 = (t & 7) * 8;      // 0..56
    const int base = (c * 16 + r) * 64 + l0;
    float4 s0 = {0.f, 0.f, 0.f, 0.f}, s1 = {0.f, 0.f, 0.f, 0.f};
#pragma unroll
    for (int w = 0; w < 4; ++w) {
        const float4* p = (const float4*)&buf[w][base];
        float4 v0 = p[0], v1 = p[1];
        s0.x += v0.x; s0.y += v0.y; s0.z += v0.z; s0.w += v0.w;
        s1.x += v1.x; s1.y += v1.y; s1.z += v1.z; s1.w += v1.w;
    }
    float v[8] = {s0.x, s0.y, s0.z, s0.w, s1.x, s1.y, s1.z, s1.w};
    const int ih = c >> 1, jh = c & 1;
    const int row = ih * 32 + (r & 3) + 8 * (r >> 2) + 4 * (l0 >> 5);
    const int col0 = jh * 32 + (l0 & 31);
    const int m = mt * 64 + row;
    const int n0g = nt * 64 + col0;
    if (gate && n0g < SDIM) {
        const float* Ep = E + m * SDIM + n0g;
#pragma unroll
        for (int j = 0; j < 8; ++j) v[j] += Ep[j];
    }
    alignas(16) __bf16 o[8];
#pragma unroll
    for (int j = 0; j < 8; ++j) o[j] = (__bf16)fmaxf(v[j], 0.f);
    const size_t frag = (size_t)(m >> 5) * (TOTAL / 16) + (n0g >> 4);
    const int lh = (m & 31) + 32 * ((n0g >> 3) & 1);
    *(ulonglong2*)(hn + frag * 512 + lh * 8) = *(const ulonglong2*)o;
    (void)accp;
}

// ---- out = h[:, 3072:] @ out_w^T + out_b (h tiled, out_w tiled padded to 1024 rows) ----
__global__ __launch_bounds__(512, 4) void k_out(const __bf16* __restrict__ h,
                                                const __bf16* __restrict__ owt,
                                                const float* __restrict__ out_b,
                                                float* __restrict__ out) {
    __shared__ float red[8][1024];
    const int wave = threadIdx.x >> 6;
    const int lane = threadIdx.x & 63;
    const int mt = blockIdx.x >> 5;
    const int ct = blockIdx.x & 31;
    const int m0 = mt * 32, c0 = ct * 32;
    const int kcA0 = (3072 / 16) + wave * 8;
    const int kcB0 = wave * 8;
    const bf16x8* Ap = (const bf16x8*)h   + ((size_t)mt * (TOTAL / 16) + kcA0) * 64 + lane;
    const bf16x8* Bp = (const bf16x8*)owt + ((size_t)ct * (1024 / 16) + kcB0) * 64 + lane;
    f32x16 acc = zero16();
#pragma unroll
    for (int i = 0; i < 8; ++i) {
        bf16x8 a = Ap[i * 64];
        bf16x8 b = Bp[i * 64];
        acc = __builtin_amdgcn_mfma_f32_32x32x16_bf16(a, b, acc, 0, 0, 0);
    }
#pragma unroll
    for (int r = 0; r < 16; ++r) {
        int row = (r & 3) + 8 * (r >> 2) + 4 * (lane >> 5);
        red[wave][row * 32 + (lane & 31)] = acc[r];
    }
    __syncthreads();
    const int e0 = threadIdx.x * 2;
    float sx = 0.f, sy = 0.f;
#pragma unroll
    for (int w = 0; w < 8; ++w) {
        float2 v = *(const float2*)&red[w][e0];
        sx += v.x; sy += v.y;
    }
    const int row = e0 >> 5, col = e0 & 31;
    const int m = m0 + row;
    const int n = c0 + col;
    if (n < NCLS)     out[m * NCLS + n]     = sx + out_b[n];
    if (n + 1 < NCLS) out[m * NCLS + n + 1] = sy + out_b[n + 1];
}

extern "C" void kernel_launch(void* const* d_in, const int* in_sizes, int n_in,
                              void* d_out, int out_size, void* d_ws, size_t ws_size,
                              hipStream_t stream) {
    const float* x     = (const float*)d_in[0];   // 256 x 2048
    const float* W     = (const float*)d_in[1];   // 4096 x 4096
    const float* in_w  = (const float*)d_in[2];   // 1024 x 2048
    const float* in_b  = (const float*)d_in[3];   // 1024
    const float* out_w = (const float*)d_in[4];   // 1000 x 1024
    const float* out_b = (const float*)d_in[5];   // 1000
    float* out = (float*)d_out;                   // 256 x 1000

    char* ws = (char*)d_ws;
    __bf16* WT  = (__bf16*)(ws + 0);          // 32 MiB  W^T tiled (r=n, c=k)
    __bf16* XT  = (__bf16*)(ws + 33554432);   // 1 MiB   x tiled
    __bf16* IWT = (__bf16*)(ws + 34603008);   // 4 MiB   in_w tiled
    __bf16* OWT = (__bf16*)(ws + 38797312);   // 2 MiB   out_w tiled (padded 1024 rows)
    float*  Ebuf= (float*)(ws + 40894464);    // 1 MiB   E f32 row-major
    __bf16* H0  = (__bf16*)(ws + 41943040);   // 2 MiB   h tiled
    __bf16* H1  = (__bf16*)(ws + 44040192);   // 2 MiB   h tiled

    k_transW_swz<<<dim3(64, 64), 256, 0, stream>>>(W, WT);
    k_swz<<<256,  256, 0, stream>>>(x,     XT,  INDIM, BATCH);
    k_swz<<<1024, 256, 0, stream>>>(in_w,  IWT, INDIM, SDIM);
    k_swz<<<512,  256, 0, stream>>>(out_w, OWT, 1024,  NCLS);
    // no H0 memset: k_gemm_E writes cols [0,1024); step t=1 reads only K<1024.

    // t = 0: h = [relu(E), 0, 0] (gate=1, h was zero)
    k_gemm_E<<<256, 512, 0, stream>>>(XT, IWT, in_b, Ebuf, H0);

    // t = 1..9 (gate fires at t=5); t=1 only needs K=1024 (h1 cols >=1024 are zero)
    const __bf16* hs = H0;
    __bf16* hd = H1;
    for (int t = 1; t < 10; ++t) {
        const int chunks = (t == 1) ? (SDIM / 16) : (TOTAL / 16);
        k_step<<<256, 512, 0, stream>>>(hs, WT, Ebuf, (t % 5 == 0) ? 1 : 0, hd, chunks);
        const __bf16* tmp = hs; hs = hd; hd = (__bf16*)tmp;
    }

    k_out<<<256, 512, 0, stream>>>(hs, OWT, out_b, out);
}